// Round 2
// baseline (242.368 us; speedup 1.0000x reference)
//
#include <hip/hip_runtime.h>
#include <stdint.h>
#include <stddef.h>

typedef int v4i __attribute__((ext_vector_type(4)));

#define BM 128
#define BN 128
#define BKB 64   // K-bytes per tile step (64 int8)

static __device__ __forceinline__ int pack4(int a, int b, int c, int d) {
    return (a & 255) | ((b & 255) << 8) | ((c & 255) << 16) | (d << 24);
}

// direct global->LDS async copy, 16B per lane, dest = wave-uniform base + lane*16
#define GLOAD16(gp, lp) __builtin_amdgcn_global_load_lds( \
    (const __attribute__((address_space(1))) void*)(gp),  \
    (__attribute__((address_space(3))) void*)(lp), 16, 0, 0)

// ---------------- pack: int32 (values in [-128,127]) -> int8 ----------------
// each thread packs 16 elements (64B read, 16B write)
__global__ __launch_bounds__(256) void pack_kernel(const int* __restrict__ src,
                                                   v4i* __restrict__ dst, int n16) {
    int i = blockIdx.x * blockDim.x + threadIdx.x;
    if (i >= n16) return;
    const v4i* s = reinterpret_cast<const v4i*>(src) + (size_t)i * 4;
    v4i v0 = s[0], v1 = s[1], v2 = s[2], v3 = s[3];
    v4i r;
    r.x = pack4(v0.x, v0.y, v0.z, v0.w);
    r.y = pack4(v1.x, v1.y, v1.z, v1.w);
    r.z = pack4(v2.x, v2.y, v2.z, v2.w);
    r.w = pack4(v3.x, v3.y, v3.z, v3.w);
    dst[i] = r;
}

// ---------------- GEMM: C = A(int8) * B(int8)^T + epilogue ----------------
// PACKED=true : A,B are packed int8 [rows][K]
// PACKED=false: A,B are int32 [rows][K], converted during LDS staging (fallback)
template <bool PACKED>
__global__ __launch_bounds__(256) void gemm_q8(
    const void* __restrict__ Ain, const void* __restrict__ Bin,
    const int* __restrict__ bias, const float* __restrict__ wscale,
    const float* __restrict__ is_p, const float* __restrict__ os_p,
    const int* __restrict__ zp_p,
    int* __restrict__ out, int Nrows, int K, int Ncols)
{
    __shared__ char Al[BM * BKB];
    __shared__ char Bl[BN * BKB];

    const int tid  = threadIdx.x;
    const int wid  = tid >> 6;
    const int lane = tid & 63;

    // XCD-aware swizzle (grid is a multiple of 8 here; guard anyway)
    const int nbc = Ncols / BN;
    int swz = blockIdx.x;
    if ((gridDim.x & 7) == 0) {
        const int cpx = gridDim.x >> 3;
        swz = (blockIdx.x & 7) * cpx + (blockIdx.x >> 3);
    }
    const int brow = swz / nbc;
    const int bcol = swz % nbc;

    const int wr = wid >> 1, wc = wid & 1;   // 2x2 wave grid, each wave 64x64 out

    v4i acc[4][4];
#pragma unroll
    for (int m = 0; m < 4; ++m)
#pragma unroll
        for (int n = 0; n < 4; ++n)
            acc[m][n] = (v4i){0, 0, 0, 0};

    // staging addresses (packed path): wave w, call i covers LDS rows w*32+i*16 .. +16
    const char* Ag = nullptr;
    const char* Bg = nullptr;
    if (PACKED) {
        Ag = (const char*)Ain + (size_t)(brow * BM + wid * 32 + (lane >> 2)) * K + (lane & 3) * 16;
        Bg = (const char*)Bin + (size_t)(bcol * BN + wid * 32 + (lane >> 2)) * K + (lane & 3) * 16;
    }
    char* aldst = Al + wid * 2048;
    char* bldst = Bl + wid * 2048;

    const int lo16 = lane & 15, hi = lane >> 4;
    const int aoff0 = (wr * 64 + lo16) * BKB + hi * 16;  // + m*16*BKB
    const int boff0 = (wc * 64 + lo16) * BKB + hi * 16;  // + n*16*BKB

    for (int k0 = 0; k0 < K; k0 += BKB) {
        if (PACKED) {
            GLOAD16(Ag + k0,           aldst);
            GLOAD16(Ag + 16 * K + k0,  aldst + 1024);
            GLOAD16(Bg + k0,           bldst);
            GLOAD16(Bg + 16 * K + k0,  bldst + 1024);
        } else {
            // fallback: read int32, pack to int8, ds_write
            const int row = tid >> 1, half = tid & 1;
            const int* sA = (const int*)Ain + (size_t)(brow * BM + row) * K + k0 + half * 32;
            const int* sB = (const int*)Bin + (size_t)(bcol * BN + row) * K + k0 + half * 32;
            int pa[8], pb[8];
#pragma unroll
            for (int j = 0; j < 8; ++j) {
                v4i va = reinterpret_cast<const v4i*>(sA)[j];
                v4i vb = reinterpret_cast<const v4i*>(sB)[j];
                pa[j] = pack4(va.x, va.y, va.z, va.w);
                pb[j] = pack4(vb.x, vb.y, vb.z, vb.w);
            }
            v4i* da = (v4i*)&Al[row * BKB + half * 32];
            da[0] = (v4i){pa[0], pa[1], pa[2], pa[3]};
            da[1] = (v4i){pa[4], pa[5], pa[6], pa[7]};
            v4i* db = (v4i*)&Bl[row * BKB + half * 32];
            db[0] = (v4i){pb[0], pb[1], pb[2], pb[3]};
            db[1] = (v4i){pb[4], pb[5], pb[6], pb[7]};
        }
        __syncthreads();   // drains vmcnt (global_load_lds) + lgkm before compute

        v4i af[4], bf[4];
#pragma unroll
        for (int m = 0; m < 4; ++m)
            af[m] = *(const v4i*)&Al[aoff0 + m * 16 * BKB];
#pragma unroll
        for (int n = 0; n < 4; ++n)
            bf[n] = *(const v4i*)&Bl[boff0 + n * 16 * BKB];
#pragma unroll
        for (int m = 0; m < 4; ++m)
#pragma unroll
            for (int n = 0; n < 4; ++n)
                acc[m][n] = __builtin_amdgcn_mfma_i32_16x16x64_i8(af[m], bf[n], acc[m][n], 0, 0, 0);

        __syncthreads();   // all reads done before next stage overwrites LDS
    }

    // ---------------- epilogue: dequant/requant, write int32 ----------------
    const float is = *is_p;
    const float os = *os_p;
    const float zp = (float)(*zp_p);
#pragma unroll
    for (int n = 0; n < 4; ++n) {
        const int col = bcol * BN + wc * 64 + n * 16 + lo16;
        const float sc = is * wscale[col] / os;
        const int   bv = bias[col];
#pragma unroll
        for (int m = 0; m < 4; ++m) {
            const int row0 = brow * BM + wr * 64 + m * 16 + hi * 4;
#pragma unroll
            for (int j = 0; j < 4; ++j) {
                float t = (float)(acc[m][n][j] + bv);
                float f = t * sc + zp;
                f = rintf(f);                       // v_rndne: half-to-even, = jnp.round
                f = fminf(fmaxf(f, -128.f), 127.f);
                out[(size_t)(row0 + j) * Ncols + col] = (int)f;
            }
        }
    }
}

extern "C" void kernel_launch(void* const* d_in, const int* in_sizes, int n_in,
                              void* d_out, int out_size, void* d_ws, size_t ws_size,
                              hipStream_t stream) {
    const int*   x32    = (const int*)d_in[0];
    const int*   w32    = (const int*)d_in[1];
    const int*   bias   = (const int*)d_in[2];
    const float* wscale = (const float*)d_in[3];
    const float* isp    = (const float*)d_in[4];
    const float* osp    = (const float*)d_in[5];
    const int*   zpp    = (const int*)d_in[6];
    int* out = (int*)d_out;

    const int OUT = in_sizes[2];            // 4096
    const int K   = in_sizes[1] / OUT;      // 4096
    const int Nr  = in_sizes[0] / K;        // 8192

    const int grid = (Nr / BM) * (OUT / BN);
    const size_t need = (size_t)Nr * K + (size_t)OUT * K;

    if (ws_size >= need) {
        char* xpk = (char*)d_ws;
        char* wpk = xpk + (size_t)Nr * K;
        const int nx16 = (Nr * K) / 16;
        const int nw16 = (OUT * K) / 16;
        pack_kernel<<<(nx16 + 255) / 256, 256, 0, stream>>>(x32, (v4i*)xpk, nx16);
        pack_kernel<<<(nw16 + 255) / 256, 256, 0, stream>>>(w32, (v4i*)wpk, nw16);
        gemm_q8<true><<<grid, 256, 0, stream>>>(xpk, wpk, bias, wscale, isp, osp, zpp,
                                                out, Nr, K, OUT);
    } else {
        gemm_q8<false><<<grid, 256, 0, stream>>>(x32, w32, bias, wscale, isp, osp, zpp,
                                                 out, Nr, K, OUT);
    }
}

// Round 3
// 187.131 us; speedup vs baseline: 1.2952x; 1.2952x over previous
//
#include <hip/hip_runtime.h>
#include <stdint.h>
#include <stddef.h>

typedef int v4i __attribute__((ext_vector_type(4)));

#define GLOAD16(gp, lp) __builtin_amdgcn_global_load_lds( \
    (const __attribute__((address_space(1))) void*)(gp),  \
    (__attribute__((address_space(3))) void*)(lp), 16, 0, 0)

#define PH_BAR()     __builtin_amdgcn_s_barrier()
#define WAIT_LGKM0() asm volatile("s_waitcnt lgkmcnt(0)" ::: "memory")
#define WAIT_VM(n)   asm volatile("s_waitcnt vmcnt(" #n ")" ::: "memory")
#define SCHED_FENCE() __builtin_amdgcn_sched_barrier(0)

static __device__ __forceinline__ int pack4(int a, int b, int c, int d) {
    return (a & 255) | ((b & 255) << 8) | ((c & 255) << 16) | (d << 24);
}

// ---------------- pack: int32 (values in [-128,127]) -> int8 ----------------
__global__ __launch_bounds__(256) void pack_kernel(const int* __restrict__ src,
                                                   v4i* __restrict__ dst, int n16) {
    int i = blockIdx.x * blockDim.x + threadIdx.x;
    if (i >= n16) return;
    const v4i* s = reinterpret_cast<const v4i*>(src) + (size_t)i * 4;
    v4i v0 = s[0], v1 = s[1], v2 = s[2], v3 = s[3];
    v4i r;
    r.x = pack4(v0.x, v0.y, v0.z, v0.w);
    r.y = pack4(v1.x, v1.y, v1.z, v1.w);
    r.z = pack4(v2.x, v2.y, v2.z, v2.w);
    r.w = pack4(v3.x, v3.y, v3.z, v3.w);
    dst[i] = r;
}

// ============ 256x256 8-phase i8 GEMM (template port of m201) ============
// A[Nrows][K] i8 packed, B[Ncols][K] i8 packed (W rows = out cols), C int32-epilogue.
// 8 waves = 2(M) x 4(N); per-wave out 128x64; K-tile = 128 bytes; 2 K-tiles/iter.
// LDS: A 2buf x [256][128] @0 (64KB), B same @65536. st-swizzle col ^= (row&7)<<4.
__global__ __launch_bounds__(512, 2) void gemm_q8_8ph(
    const char* __restrict__ Apk, const char* __restrict__ Bpk,
    const int* __restrict__ bias, const float* __restrict__ wscale,
    const float* __restrict__ is_p, const float* __restrict__ os_p,
    const int* __restrict__ zp_p,
    int* __restrict__ out, int K, int Ncols)
{
    __shared__ char lds[131072];

    const int tid  = threadIdx.x;
    const int wid  = tid >> 6;
    const int lane = tid & 63;
    const int l7 = lane & 7, l3 = lane >> 3;
    const int lo16 = lane & 15, hi = lane >> 4;

    // bijective XCD-aware swizzle (m204)
    int swz;
    {
        const int nwg = gridDim.x;
        const int q = nwg >> 3, r = nwg & 7;
        const int xcd = blockIdx.x & 7;
        const int base = (xcd < r) ? xcd * (q + 1) : r * (q + 1) + (xcd - r) * q;
        swz = base + (blockIdx.x >> 3);
    }
    const int nbc  = Ncols >> 8;
    const int brow = swz / nbc, bcol = swz % nbc;

    const int wr = wid >> 2, wc = wid & 3;

    // staging: wave covers rows wid*8+l3 (+64*li, +128*h); source chunk pre-swizzled
    const char* Ab = Apk + (size_t)(brow * 256 + wid * 8 + l3) * K + ((l7 ^ l3) << 4);
    const char* Bb = Bpk + (size_t)(bcol * 256 + wid * 8 + l3) * K + ((l7 ^ l3) << 4);

    // ds_read: row = (block row) + lo16, col = s*64 + hi*16, swizzled by (row&7)=l7
    const int colsw0 = (hi << 4) ^ (l7 << 4);
    const int colsw1 = colsw0 ^ 64;
    const int aRow = ((wr << 7) + lo16) << 7;   // (wr*128+lo16)*128
    const int bRow = ((wc << 6) + lo16) << 7;   // (wc*64+lo16)*128

    v4i acc[8][4];
#pragma unroll
    for (int m = 0; m < 8; ++m)
#pragma unroll
        for (int n = 0; n < 4; ++n)
            acc[m][n] = (v4i){0, 0, 0, 0};

    v4i af[4][2], bf[2][2], bf2[2][2];

    // stage one 16KB half-tile: 2 x global_load_lds per thread
    auto stage = [&](const char* gb, int ldsOp, int bufo, int h, int t) {
        const char* g = gb + (size_t)(h * 128) * K + ((size_t)t << 7);
        char* l = lds + (ldsOp + bufo + (h << 14) + (wid << 10));
        GLOAD16(g, l);
        GLOAD16(g + (size_t)64 * K, l + 8192);
    };
    auto ldA = [&](int bufo, int mh) {
#pragma unroll
        for (int m = 0; m < 4; ++m) {
            const int base = bufo + aRow + (mh << 13) + (m << 11);
            af[m][0] = *(const v4i*)(lds + base + colsw0);
            af[m][1] = *(const v4i*)(lds + base + colsw1);
        }
    };
    auto ldB = [&](v4i (&bx)[2][2], int bufo, int n0) {
#pragma unroll
        for (int n = 0; n < 2; ++n) {
            const int base = 65536 + bufo + bRow + ((n0 + n) << 11);
            bx[n][0] = *(const v4i*)(lds + base + colsw0);
            bx[n][1] = *(const v4i*)(lds + base + colsw1);
        }
    };

#define MFMA_Q(mo, bfx, no) do {                                                  \
    _Pragma("unroll") for (int m_ = 0; m_ < 4; ++m_)                              \
    _Pragma("unroll") for (int n_ = 0; n_ < 2; ++n_)                              \
    _Pragma("unroll") for (int s_ = 0; s_ < 2; ++s_)                              \
        acc[(mo) + m_][(no) + n_] = __builtin_amdgcn_mfma_i32_16x16x64_i8(        \
            af[m_][s_], bfx[n_][s_], acc[(mo) + m_][(no) + n_], 0, 0, 0);         \
} while (0)

    // ---- prologue: tile0 full (8 loads) + tile1.B (4 loads); keep 4 in flight ----
    stage(Ab, 0,     0,     0, 0);  stage(Ab, 0,     0,     1, 0);
    stage(Bb, 65536, 0,     0, 0);  stage(Bb, 65536, 0,     1, 0);
    stage(Bb, 65536, 32768, 0, 1);  stage(Bb, 65536, 32768, 1, 1);
    WAIT_VM(4);
    PH_BAR();

    const int niter = K >> 8;   // 2 K-tiles (256 bytes of K) per iter
    for (int i = 0; i < niter; ++i) {
        SCHED_FENCE();
        const bool last = (i == niter - 1);
        const int tO1 = 2 * i + 1;            // this iter's odd tile (A staged P1,P2)
        const int tE  = 2 * i + 2, tO = 2 * i + 3;

        // ---- P1: even tile, quadrant mh0 x n01 ----
        ldA(0, 0);
        ldB(bf, 0, 0);
        stage(Ab, 0, 32768, 0, tO1);
        PH_BAR(); WAIT_LGKM0();
        __builtin_amdgcn_s_setprio(1); MFMA_Q(0, bf, 0); __builtin_amdgcn_s_setprio(0);
        PH_BAR();
        // ---- P2: mh0 x n23 ----
        ldB(bf2, 0, 2);
        stage(Ab, 0, 32768, 1, tO1);
        PH_BAR(); WAIT_LGKM0();
        __builtin_amdgcn_s_setprio(1); MFMA_Q(0, bf2, 2); __builtin_amdgcn_s_setprio(0);
        PH_BAR();
        // ---- P3: mh1 x n01 ----
        ldA(0, 1);
        if (!last) stage(Bb, 65536, 0, 0, tE);
        PH_BAR(); WAIT_LGKM0();
        __builtin_amdgcn_s_setprio(1); MFMA_Q(4, bf, 0); __builtin_amdgcn_s_setprio(0);
        PH_BAR();
        // ---- P4: mh1 x n23 ; counted vmcnt before barrier ----
        if (!last) stage(Bb, 65536, 0, 1, tE);
        PH_BAR();
        __builtin_amdgcn_s_setprio(1); MFMA_Q(4, bf2, 2); __builtin_amdgcn_s_setprio(0);
        if (last) { WAIT_VM(0); } else { WAIT_VM(4); }
        PH_BAR();
        SCHED_FENCE();
        // ---- P5: odd tile, mh0 x n01 ----
        ldA(32768, 0);
        ldB(bf, 32768, 0);
        if (!last) stage(Ab, 0, 0, 0, tE);
        PH_BAR(); WAIT_LGKM0();
        __builtin_amdgcn_s_setprio(1); MFMA_Q(0, bf, 0); __builtin_amdgcn_s_setprio(0);
        PH_BAR();
        // ---- P6: mh0 x n23 ----
        ldB(bf2, 32768, 2);
        if (!last) stage(Ab, 0, 0, 1, tE);
        PH_BAR(); WAIT_LGKM0();
        __builtin_amdgcn_s_setprio(1); MFMA_Q(0, bf2, 2); __builtin_amdgcn_s_setprio(0);
        PH_BAR();
        // ---- P7: mh1 x n01 ----
        ldA(32768, 1);
        if (!last) stage(Bb, 65536, 32768, 0, tO);
        PH_BAR(); WAIT_LGKM0();
        __builtin_amdgcn_s_setprio(1); MFMA_Q(4, bf, 0); __builtin_amdgcn_s_setprio(0);
        PH_BAR();
        // ---- P8: mh1 x n23 ; counted vmcnt before barrier ----
        if (!last) stage(Bb, 65536, 32768, 1, tO);
        PH_BAR();
        __builtin_amdgcn_s_setprio(1); MFMA_Q(4, bf2, 2); __builtin_amdgcn_s_setprio(0);
        if (!last) { WAIT_VM(4); }
        PH_BAR();
    }
#undef MFMA_Q

    // ---------------- epilogue ----------------
    const float is = *is_p, os = *os_p;
    const float zp = (float)(*zp_p);
#pragma unroll
    for (int n = 0; n < 4; ++n) {
        const int col = (bcol << 8) + (wc << 6) + (n << 4) + lo16;
        const float sc = is * wscale[col] / os;
        const int   bv = bias[col];
#pragma unroll
        for (int m = 0; m < 8; ++m) {
            const int row0 = (brow << 8) + (wr << 7) + (m << 4) + (hi << 2);
#pragma unroll
            for (int j = 0; j < 4; ++j) {
                float f = (float)(acc[m][n][j] + bv) * sc + zp;
                f = rintf(f);
                f = fminf(fmaxf(f, -128.f), 127.f);
                out[(size_t)(row0 + j) * Ncols + col] = (int)f;
            }
        }
    }
}

// ---------------- fallback 128^2 2-barrier kernel (known-correct) ----------------
template <bool PACKED>
__global__ __launch_bounds__(256) void gemm_q8(
    const void* __restrict__ Ain, const void* __restrict__ Bin,
    const int* __restrict__ bias, const float* __restrict__ wscale,
    const float* __restrict__ is_p, const float* __restrict__ os_p,
    const int* __restrict__ zp_p,
    int* __restrict__ out, int Nrows, int K, int Ncols)
{
    __shared__ char Al[128 * 64];
    __shared__ char Bl[128 * 64];

    const int tid  = threadIdx.x;
    const int wid  = tid >> 6;
    const int lane = tid & 63;

    const int nbc = Ncols / 128;
    int swz = blockIdx.x;
    if ((gridDim.x & 7) == 0) {
        const int cpx = gridDim.x >> 3;
        swz = (blockIdx.x & 7) * cpx + (blockIdx.x >> 3);
    }
    const int brow = swz / nbc;
    const int bcol = swz % nbc;
    const int wr = wid >> 1, wc = wid & 1;

    v4i acc[4][4];
#pragma unroll
    for (int m = 0; m < 4; ++m)
#pragma unroll
        for (int n = 0; n < 4; ++n)
            acc[m][n] = (v4i){0, 0, 0, 0};

    const char* Ag = nullptr;
    const char* Bg = nullptr;
    if (PACKED) {
        Ag = (const char*)Ain + (size_t)(brow * 128 + wid * 32 + (lane >> 2)) * K + (lane & 3) * 16;
        Bg = (const char*)Bin + (size_t)(bcol * 128 + wid * 32 + (lane >> 2)) * K + (lane & 3) * 16;
    }
    char* aldst = Al + wid * 2048;
    char* bldst = Bl + wid * 2048;

    const int lo16 = lane & 15, hi = lane >> 4;
    const int aoff0 = (wr * 64 + lo16) * 64 + hi * 16;
    const int boff0 = (wc * 64 + lo16) * 64 + hi * 16;

    for (int k0 = 0; k0 < K; k0 += 64) {
        if (PACKED) {
            GLOAD16(Ag + k0,          aldst);
            GLOAD16(Ag + 16 * K + k0, aldst + 1024);
            GLOAD16(Bg + k0,          bldst);
            GLOAD16(Bg + 16 * K + k0, bldst + 1024);
        } else {
            const int row = tid >> 1, half = tid & 1;
            const int* sA = (const int*)Ain + (size_t)(brow * 128 + row) * K + k0 + half * 32;
            const int* sB = (const int*)Bin + (size_t)(bcol * 128 + row) * K + k0 + half * 32;
            int pa[8], pb[8];
#pragma unroll
            for (int j = 0; j < 8; ++j) {
                v4i va = reinterpret_cast<const v4i*>(sA)[j];
                v4i vb = reinterpret_cast<const v4i*>(sB)[j];
                pa[j] = pack4(va.x, va.y, va.z, va.w);
                pb[j] = pack4(vb.x, vb.y, vb.z, vb.w);
            }
            v4i* da = (v4i*)&Al[row * 64 + half * 32];
            da[0] = (v4i){pa[0], pa[1], pa[2], pa[3]};
            da[1] = (v4i){pa[4], pa[5], pa[6], pa[7]};
            v4i* db = (v4i*)&Bl[row * 64 + half * 32];
            db[0] = (v4i){pb[0], pb[1], pb[2], pb[3]};
            db[1] = (v4i){pb[4], pb[5], pb[6], pb[7]};
        }
        __syncthreads();

        v4i af[4], bfr[4];
#pragma unroll
        for (int m = 0; m < 4; ++m)
            af[m] = *(const v4i*)&Al[aoff0 + m * 16 * 64];
#pragma unroll
        for (int n = 0; n < 4; ++n)
            bfr[n] = *(const v4i*)&Bl[boff0 + n * 16 * 64];
#pragma unroll
        for (int m = 0; m < 4; ++m)
#pragma unroll
            for (int n = 0; n < 4; ++n)
                acc[m][n] = __builtin_amdgcn_mfma_i32_16x16x64_i8(af[m], bfr[n], acc[m][n], 0, 0, 0);

        __syncthreads();
    }

    const float is = *is_p;
    const float os = *os_p;
    const float zp = (float)(*zp_p);
#pragma unroll
    for (int n = 0; n < 4; ++n) {
        const int col = bcol * 128 + wc * 64 + n * 16 + lo16;
        const float sc = is * wscale[col] / os;
        const int   bv = bias[col];
#pragma unroll
        for (int m = 0; m < 4; ++m) {
            const int row0 = brow * 128 + wr * 64 + m * 16 + hi * 4;
#pragma unroll
            for (int j = 0; j < 4; ++j) {
                float f = (float)(acc[m][n][j] + bv) * sc + zp;
                f = rintf(f);
                f = fminf(fmaxf(f, -128.f), 127.f);
                out[(size_t)(row0 + j) * Ncols + col] = (int)f;
            }
        }
    }
}

extern "C" void kernel_launch(void* const* d_in, const int* in_sizes, int n_in,
                              void* d_out, int out_size, void* d_ws, size_t ws_size,
                              hipStream_t stream) {
    const int*   x32    = (const int*)d_in[0];
    const int*   w32    = (const int*)d_in[1];
    const int*   bias   = (const int*)d_in[2];
    const float* wscale = (const float*)d_in[3];
    const float* isp    = (const float*)d_in[4];
    const float* osp    = (const float*)d_in[5];
    const int*   zpp    = (const int*)d_in[6];
    int* out = (int*)d_out;

    const int OUT = in_sizes[2];            // 4096
    const int K   = in_sizes[1] / OUT;      // 4096
    const int Nr  = in_sizes[0] / K;        // 8192

    const size_t need = (size_t)Nr * K + (size_t)OUT * K;

    if (ws_size >= need) {
        char* xpk = (char*)d_ws;
        char* wpk = xpk + (size_t)Nr * K;
        const int nx16 = (Nr * K) / 16;
        const int nw16 = (OUT * K) / 16;
        pack_kernel<<<(nx16 + 255) / 256, 256, 0, stream>>>(x32, (v4i*)xpk, nx16);
        pack_kernel<<<(nw16 + 255) / 256, 256, 0, stream>>>(w32, (v4i*)wpk, nw16);
        if ((Nr & 255) == 0 && (OUT & 255) == 0 && (K & 255) == 0) {
            const int grid8 = (Nr / 256) * (OUT / 256);
            gemm_q8_8ph<<<grid8, 512, 0, stream>>>(xpk, wpk, bias, wscale, isp, osp, zpp,
                                                   out, K, OUT);
        } else {
            const int grid = (Nr / 128) * (OUT / 128);
            gemm_q8<true><<<grid, 256, 0, stream>>>(xpk, wpk, bias, wscale, isp, osp, zpp,
                                                    out, Nr, K, OUT);
        }
    } else {
        const int grid = (Nr / 128) * (OUT / 128);
        gemm_q8<false><<<grid, 256, 0, stream>>>(x32, w32, bias, wscale, isp, osp, zpp,
                                                 out, Nr, K, OUT);
    }
}

// Round 4
// 176.789 us; speedup vs baseline: 1.3709x; 1.0585x over previous
//
#include <hip/hip_runtime.h>
#include <stdint.h>
#include <stddef.h>

typedef int v4i __attribute__((ext_vector_type(4)));

#define GLOAD16(gp, lp) __builtin_amdgcn_global_load_lds( \
    (const __attribute__((address_space(1))) void*)(gp),  \
    (__attribute__((address_space(3))) void*)(lp), 16, 0, 0)

#define PH_BAR()     __builtin_amdgcn_s_barrier()
#define WAIT_LGKM0() asm volatile("s_waitcnt lgkmcnt(0)" ::: "memory")
#define WAIT_VM(n)   asm volatile("s_waitcnt vmcnt(" #n ")" ::: "memory")
#define SCHED_FENCE() __builtin_amdgcn_sched_barrier(0)
#define PRIO1() __builtin_amdgcn_s_setprio(1)
#define PRIO0() __builtin_amdgcn_s_setprio(0)

static __device__ __forceinline__ int pack4(int a, int b, int c, int d) {
    return (a & 255) | ((b & 255) << 8) | ((c & 255) << 16) | (d << 24);
}

// ---------------- pack: int32 (values in [-128,127]) -> int8, both arrays ----------------
__global__ __launch_bounds__(256) void pack2_kernel(const int* __restrict__ srcA, v4i* __restrict__ dstA, int nA,
                                                    const int* __restrict__ srcB, v4i* __restrict__ dstB, int nB) {
    int i = blockIdx.x * blockDim.x + threadIdx.x;
    const int* src; v4i* dst;
    if (i < nA) { src = srcA; dst = dstA; }
    else { i -= nA; if (i >= nB) return; src = srcB; dst = dstB; }
    const v4i* s = reinterpret_cast<const v4i*>(src) + (size_t)i * 4;
    v4i v0 = s[0], v1 = s[1], v2 = s[2], v3 = s[3];
    v4i r;
    r.x = pack4(v0.x, v0.y, v0.z, v0.w);
    r.y = pack4(v1.x, v1.y, v1.z, v1.w);
    r.z = pack4(v2.x, v2.y, v2.z, v2.w);
    r.w = pack4(v3.x, v3.y, v3.z, v3.w);
    dst[i] = r;
}

// ============ 256x256 8-phase i8 GEMM (m201 template, balanced reads) ============
// A[Nrows][K] i8 packed, B[Ncols][K] i8 packed (W rows = out cols), int32 epilogue out.
// 8 waves = 2(M) x 4(N); per-wave out 128x64; K-tile = 128 bytes; 2 K-tiles/iter.
// LDS: A 2buf x [256][128] @0 (64KB), B same @65536. st-swizzle chunk16 ^= (row&7).
// Read balance: 8/4/8/4... per phase; B-n01 of NEXT tile read-ahead in P4/P8, with
// vmcnt(6) moved to END of P3/P7 (wait -> barrier -> read, cross-wave safe).
__global__ __launch_bounds__(512, 2) void gemm_q8_8ph(
    const char* __restrict__ Apk, const char* __restrict__ Bpk,
    const int* __restrict__ bias, const float* __restrict__ wscale,
    const float* __restrict__ is_p, const float* __restrict__ os_p,
    const int* __restrict__ zp_p,
    int* __restrict__ out, int K, int Ncols)
{
    __shared__ char lds[131072];

    const int tid  = threadIdx.x;
    const int wid  = tid >> 6;
    const int lane = tid & 63;
    const int l7 = lane & 7, l3 = lane >> 3;
    const int lo16 = lane & 15, hi = lane >> 4;

    // bijective XCD-aware swizzle (m204)
    int swz;
    {
        const int nwg = gridDim.x;
        const int q = nwg >> 3, r = nwg & 7;
        const int xcd = blockIdx.x & 7;
        const int base = (xcd < r) ? xcd * (q + 1) : r * (q + 1) + (xcd - r) * q;
        swz = base + (blockIdx.x >> 3);
    }
    const int nbc  = Ncols >> 8;
    const int brow = swz / nbc, bcol = swz % nbc;

    const int wr = wid >> 2, wc = wid & 3;

    // staging: wave wid covers rows wid*8+l3 (+64 per 2nd load, +128*h); source pre-swizzled
    const char* Ab = Apk + (size_t)(brow * 256 + wid * 8 + l3) * K + ((l7 ^ l3) << 4);
    const char* Bb = Bpk + (size_t)(bcol * 256 + wid * 8 + l3) * K + ((l7 ^ l3) << 4);

    // ds_read: row offset lo16 within block, col = slice*64 + hi*16, chunk-swizzled by row&7
    const int colsw0 = (hi << 4) ^ (l7 << 4);
    const int colsw1 = colsw0 ^ 64;
    const int aRow = ((wr << 7) + lo16) << 7;   // (wr*128+lo16)*128
    const int bRow = ((wc << 6) + lo16) << 7;   // (wc*64+lo16)*128

    v4i acc[8][4];
#pragma unroll
    for (int m = 0; m < 8; ++m)
#pragma unroll
        for (int n = 0; n < 4; ++n)
            acc[m][n] = (v4i){0, 0, 0, 0};

    v4i af[4][2], bf[2][2], bf2[2][2];

    auto stage = [&](const char* gb, int ldsOp, int bufo, int h, int t) {
        const char* g = gb + (size_t)(h * 128) * K + ((size_t)t << 7);
        char* l = lds + (ldsOp + bufo + (h << 14) + (wid << 10));
        GLOAD16(g, l);
        GLOAD16(g + (size_t)64 * K, l + 8192);
    };
    auto ldA = [&](int bufo, int mh) {
#pragma unroll
        for (int m = 0; m < 4; ++m) {
            const int base = bufo + aRow + (mh << 13) + (m << 11);
            af[m][0] = *(const v4i*)(lds + base + colsw0);
            af[m][1] = *(const v4i*)(lds + base + colsw1);
        }
    };
    auto ldB = [&](v4i (&bx)[2][2], int bufo, int n0) {
#pragma unroll
        for (int n = 0; n < 2; ++n) {
            const int base = 65536 + bufo + bRow + ((n0 + n) << 11);
            bx[n][0] = *(const v4i*)(lds + base + colsw0);
            bx[n][1] = *(const v4i*)(lds + base + colsw1);
        }
    };

#define MFMA_Q(mo, bfx, no) do {                                                  \
    _Pragma("unroll") for (int m_ = 0; m_ < 4; ++m_)                              \
    _Pragma("unroll") for (int n_ = 0; n_ < 2; ++n_)                              \
    _Pragma("unroll") for (int s_ = 0; s_ < 2; ++s_)                              \
        acc[(mo) + m_][(no) + n_] = __builtin_amdgcn_mfma_i32_16x16x64_i8(        \
            af[m_][s_], bfx[n_][s_], acc[(mo) + m_][(no) + n_], 0, 0, 0);         \
} while (0)

    // ---- prologue: tile0 A+B (8 loads) + tile1 B (4 loads); preload bf(even n01) ----
    stage(Ab, 0,     0,     0, 0);  stage(Ab, 0,     0,     1, 0);
    stage(Bb, 65536, 0,     0, 0);  stage(Bb, 65536, 0,     1, 0);
    stage(Bb, 65536, 32768, 0, 1);  stage(Bb, 65536, 32768, 1, 1);
    WAIT_VM(4);           // tile0 A+B landed; tile1 B (4) outstanding
    PH_BAR();
    ldB(bf, 0, 0);        // even-tile n01 (covered by P1's lgkmcnt(0))

    const int niter = K >> 8;   // 2 K-tiles (256 B of K) per iteration
    for (int i = 0; i < niter - 1; ++i) {
        SCHED_FENCE();
        const int tO1 = 2 * i + 1, tE = 2 * i + 2, tO = 2 * i + 3;

        // P1: even mh0 x n01   [8 reads]
        ldA(0, 0);
        stage(Ab, 0, 32768, 0, tO1);
        PH_BAR(); WAIT_LGKM0();
        PRIO1(); MFMA_Q(0, bf, 0); PRIO0();
        PH_BAR();
        // P2: even mh0 x n23   [4 reads]
        ldB(bf2, 0, 2);
        stage(Ab, 0, 32768, 1, tO1);
        PH_BAR(); WAIT_LGKM0();
        PRIO1(); MFMA_Q(0, bf2, 2); PRIO0();
        PH_BAR();
        // P3: even mh1 x n01   [8 reads]; vmcnt(6) drains odd-B before P4's read-ahead
        ldA(0, 1);
        stage(Bb, 65536, 0, 0, tE);
        PH_BAR(); WAIT_LGKM0();
        PRIO1(); MFMA_Q(4, bf, 0); PRIO0();
        WAIT_VM(6);
        PH_BAR();
        // P4: even mh1 x n23   [4 reads: odd-tile n01 read-ahead]
        ldB(bf, 32768, 0);
        stage(Bb, 65536, 0, 1, tE);
        PH_BAR();
        PRIO1(); MFMA_Q(4, bf2, 2); PRIO0();
        WAIT_VM(4);
        PH_BAR();
        SCHED_FENCE();
        // P5: odd mh0 x n01    [8 reads]
        ldA(32768, 0);
        stage(Ab, 0, 0, 0, tE);
        PH_BAR(); WAIT_LGKM0();
        PRIO1(); MFMA_Q(0, bf, 0); PRIO0();
        PH_BAR();
        // P6: odd mh0 x n23    [4 reads]
        ldB(bf2, 32768, 2);
        stage(Ab, 0, 0, 1, tE);
        PH_BAR(); WAIT_LGKM0();
        PRIO1(); MFMA_Q(0, bf2, 2); PRIO0();
        PH_BAR();
        // P7: odd mh1 x n01    [8 reads]; vmcnt(6) drains next-even-B before P8's read-ahead
        ldA(32768, 1);
        stage(Bb, 65536, 32768, 0, tO);
        PH_BAR(); WAIT_LGKM0();
        PRIO1(); MFMA_Q(4, bf, 0); PRIO0();
        WAIT_VM(6);
        PH_BAR();
        // P8: odd mh1 x n23    [4 reads: next-even n01 read-ahead]
        ldB(bf, 0, 0);
        stage(Bb, 65536, 32768, 1, tO);
        PH_BAR();
        PRIO1(); MFMA_Q(4, bf2, 2); PRIO0();
        WAIT_VM(4);
        PH_BAR();
    }

    // ---- peeled last iteration: stage only its own odd-A; single vmcnt(0) ----
    {
        SCHED_FENCE();
        const int tL = 2 * niter - 1;
        // L1
        ldA(0, 0);
        stage(Ab, 0, 32768, 0, tL);
        PH_BAR(); WAIT_LGKM0();
        PRIO1(); MFMA_Q(0, bf, 0); PRIO0();
        PH_BAR();
        // L2
        ldB(bf2, 0, 2);
        stage(Ab, 0, 32768, 1, tL);
        PH_BAR(); WAIT_LGKM0();
        PRIO1(); MFMA_Q(0, bf2, 2); PRIO0();
        PH_BAR();
        // L3 ; drain everything (odd-B from prev P7/P8 + odd-A from L1/L2)
        ldA(0, 1);
        PH_BAR(); WAIT_LGKM0();
        PRIO1(); MFMA_Q(4, bf, 0); PRIO0();
        WAIT_VM(0);
        PH_BAR();
        // L4
        ldB(bf, 32768, 0);
        PH_BAR();
        PRIO1(); MFMA_Q(4, bf2, 2); PRIO0();
        PH_BAR();
        // L5
        ldA(32768, 0);
        PH_BAR(); WAIT_LGKM0();
        PRIO1(); MFMA_Q(0, bf, 0); PRIO0();
        PH_BAR();
        // L6
        ldB(bf2, 32768, 2);
        PH_BAR(); WAIT_LGKM0();
        PRIO1(); MFMA_Q(0, bf2, 2); PRIO0();
        PH_BAR();
        // L7
        ldA(32768, 1);
        PH_BAR(); WAIT_LGKM0();
        PRIO1(); MFMA_Q(4, bf, 0); PRIO0();
        PH_BAR();
        // L8
        PRIO1(); MFMA_Q(4, bf2, 2); PRIO0();
    }
#undef MFMA_Q

    // ---------------- epilogue: row-major store order, scales hoisted ----------------
    const float is = *is_p, os = *os_p;
    const float zp = (float)(*zp_p);
    const int colb = (bcol << 8) + (wc << 6) + lo16;
    float sc[4]; int bv[4];
#pragma unroll
    for (int n = 0; n < 4; ++n) {
        sc[n] = is * wscale[colb + (n << 4)] / os;
        bv[n] = bias[colb + (n << 4)];
    }
#pragma unroll
    for (int m = 0; m < 8; ++m) {
#pragma unroll
        for (int j = 0; j < 4; ++j) {
            const int row = (brow << 8) + (wr << 7) + (m << 4) + (hi << 2) + j;
            int* op = out + (size_t)row * Ncols + colb;
#pragma unroll
            for (int n = 0; n < 4; ++n) {
                float f = (float)(acc[m][n][j] + bv[n]) * sc[n] + zp;
                f = rintf(f);
                f = fminf(fmaxf(f, -128.f), 127.f);
                op[n << 4] = (int)f;
            }
        }
    }
}

// ---------------- fallback 128^2 2-barrier kernel (known-correct) ----------------
template <bool PACKED>
__global__ __launch_bounds__(256) void gemm_q8(
    const void* __restrict__ Ain, const void* __restrict__ Bin,
    const int* __restrict__ bias, const float* __restrict__ wscale,
    const float* __restrict__ is_p, const float* __restrict__ os_p,
    const int* __restrict__ zp_p,
    int* __restrict__ out, int Nrows, int K, int Ncols)
{
    __shared__ char Al[128 * 64];
    __shared__ char Bl[128 * 64];

    const int tid  = threadIdx.x;
    const int wid  = tid >> 6;
    const int lane = tid & 63;

    const int nbc = Ncols / 128;
    int swz = blockIdx.x;
    if ((gridDim.x & 7) == 0) {
        const int cpx = gridDim.x >> 3;
        swz = (blockIdx.x & 7) * cpx + (blockIdx.x >> 3);
    }
    const int brow = swz / nbc;
    const int bcol = swz % nbc;
    const int wr = wid >> 1, wc = wid & 1;

    v4i acc[4][4];
#pragma unroll
    for (int m = 0; m < 4; ++m)
#pragma unroll
        for (int n = 0; n < 4; ++n)
            acc[m][n] = (v4i){0, 0, 0, 0};

    const char* Ag = nullptr;
    const char* Bg = nullptr;
    if (PACKED) {
        Ag = (const char*)Ain + (size_t)(brow * 128 + wid * 32 + (lane >> 2)) * K + (lane & 3) * 16;
        Bg = (const char*)Bin + (size_t)(bcol * 128 + wid * 32 + (lane >> 2)) * K + (lane & 3) * 16;
    }
    char* aldst = Al + wid * 2048;
    char* bldst = Bl + wid * 2048;

    const int lo16 = lane & 15, hi = lane >> 4;
    const int aoff0 = (wr * 64 + lo16) * 64 + hi * 16;
    const int boff0 = (wc * 64 + lo16) * 64 + hi * 16;

    for (int k0 = 0; k0 < K; k0 += 64) {
        if (PACKED) {
            GLOAD16(Ag + k0,          aldst);
            GLOAD16(Ag + 16 * K + k0, aldst + 1024);
            GLOAD16(Bg + k0,          bldst);
            GLOAD16(Bg + 16 * K + k0, bldst + 1024);
        } else {
            const int row = tid >> 1, half = tid & 1;
            const int* sA = (const int*)Ain + (size_t)(brow * 128 + row) * K + k0 + half * 32;
            const int* sB = (const int*)Bin + (size_t)(bcol * 128 + row) * K + k0 + half * 32;
            int pa[8], pb[8];
#pragma unroll
            for (int j = 0; j < 8; ++j) {
                v4i va = reinterpret_cast<const v4i*>(sA)[j];
                v4i vb = reinterpret_cast<const v4i*>(sB)[j];
                pa[j] = pack4(va.x, va.y, va.z, va.w);
                pb[j] = pack4(vb.x, vb.y, vb.z, vb.w);
            }
            v4i* da = (v4i*)&Al[row * 64 + half * 32];
            da[0] = (v4i){pa[0], pa[1], pa[2], pa[3]};
            da[1] = (v4i){pa[4], pa[5], pa[6], pa[7]};
            v4i* db = (v4i*)&Bl[row * 64 + half * 32];
            db[0] = (v4i){pb[0], pb[1], pb[2], pb[3]};
            db[1] = (v4i){pb[4], pb[5], pb[6], pb[7]};
        }
        __syncthreads();

        v4i af[4], bfr[4];
#pragma unroll
        for (int m = 0; m < 4; ++m)
            af[m] = *(const v4i*)&Al[aoff0 + m * 16 * 64];
#pragma unroll
        for (int n = 0; n < 4; ++n)
            bfr[n] = *(const v4i*)&Bl[boff0 + n * 16 * 64];
#pragma unroll
        for (int m = 0; m < 4; ++m)
#pragma unroll
            for (int n = 0; n < 4; ++n)
                acc[m][n] = __builtin_amdgcn_mfma_i32_16x16x64_i8(af[m], bfr[n], acc[m][n], 0, 0, 0);

        __syncthreads();
    }

    const float is = *is_p;
    const float os = *os_p;
    const float zp = (float)(*zp_p);
#pragma unroll
    for (int n = 0; n < 4; ++n) {
        const int col = bcol * 128 + wc * 64 + n * 16 + lo16;
        const float sc = is * wscale[col] / os;
        const int   bv = bias[col];
#pragma unroll
        for (int m = 0; m < 4; ++m) {
            const int row0 = brow * 128 + wr * 64 + m * 16 + hi * 4;
#pragma unroll
            for (int j = 0; j < 4; ++j) {
                float f = (float)(acc[m][n][j] + bv) * sc + zp;
                f = rintf(f);
                f = fminf(fmaxf(f, -128.f), 127.f);
                out[(size_t)(row0 + j) * Ncols + col] = (int)f;
            }
        }
    }
}

extern "C" void kernel_launch(void* const* d_in, const int* in_sizes, int n_in,
                              void* d_out, int out_size, void* d_ws, size_t ws_size,
                              hipStream_t stream) {
    const int*   x32    = (const int*)d_in[0];
    const int*   w32    = (const int*)d_in[1];
    const int*   bias   = (const int*)d_in[2];
    const float* wscale = (const float*)d_in[3];
    const float* isp    = (const float*)d_in[4];
    const float* osp    = (const float*)d_in[5];
    const int*   zpp    = (const int*)d_in[6];
    int* out = (int*)d_out;

    const int OUT = in_sizes[2];            // 4096
    const int K   = in_sizes[1] / OUT;      // 4096
    const int Nr  = in_sizes[0] / K;        // 8192

    const size_t need = (size_t)Nr * K + (size_t)OUT * K;

    if (ws_size >= need) {
        char* xpk = (char*)d_ws;
        char* wpk = xpk + (size_t)Nr * K;
        const int nx16 = (Nr * K) / 16;
        const int nw16 = (OUT * K) / 16;
        pack2_kernel<<<(nx16 + nw16 + 255) / 256, 256, 0, stream>>>(
            x32, (v4i*)xpk, nx16, w32, (v4i*)wpk, nw16);
        if ((Nr & 255) == 0 && (OUT & 255) == 0 && (K & 511) == 0) {
            const int grid8 = (Nr / 256) * (OUT / 256);
            gemm_q8_8ph<<<grid8, 512, 0, stream>>>(xpk, wpk, bias, wscale, isp, osp, zpp,
                                                   out, K, OUT);
        } else {
            const int grid = (Nr / 128) * (OUT / 128);
            gemm_q8<true><<<grid, 256, 0, stream>>>(xpk, wpk, bias, wscale, isp, osp, zpp,
                                                    out, Nr, K, OUT);
        }
    } else {
        const int grid = (Nr / 128) * (OUT / 128);
        gemm_q8<false><<<grid, 256, 0, stream>>>(x32, w32, bias, wscale, isp, osp, zpp,
                                                 out, Nr, K, OUT);
    }
}